// Round 18
// baseline (166.500 us; speedup 1.0000x reference)
//
#include <hip/hip_runtime.h>

#define HH 192
#define WW 256
#define HW (HH * WW)
#define NCHUNK 16
#define THREADS 512
#define CH4 (4 * HW)          // global float advance per 4-channel chunk
#define ROWD 264              // pair-dwords per band row (cols -4..259)
#define CPD (8 * ROWD)        // 2112 dwords per cpair block
#define BUFD (2 * CPD)        // 4224 dwords per buffer
#define UPW 132               // staged 16B-units per wave per chunk

typedef float f4 __attribute__((ext_vector_type(4)));
typedef unsigned int u32;
typedef u32 u4 __attribute__((ext_vector_type(4)));
typedef _Float16 h2 __attribute__((ext_vector_type(2)));

// fp16 dot2 with fp32 accumulate: d = a.x*b.x + a.y*b.y + c
static __device__ __forceinline__ float dot2f(u32 a, u32 b, float c) {
#if __has_builtin(__builtin_amdgcn_fdot2)
    return __builtin_amdgcn_fdot2(__builtin_bit_cast(h2, a),
                                  __builtin_bit_cast(h2, b), c, false);
#else
    float d;
    asm("v_dot2_f32_f16 %0, %1, %2, %3" : "=v"(d) : "v"(a), "v"(b), "v"(c));
    return d;
#endif
}
// pack two f32 -> two f16 in one dword (RTZ)
static __device__ __forceinline__ u32 pkh(float lo, float hi) {
    return __builtin_bit_cast(u32, __builtin_amdgcn_cvt_pkrtz(lo, hi));
}

// R18: halve the LDS volume (the measured invariant pinning R8/R11/R13/R17
// at 112-119us) by packing channel-PAIRS as fp16 and consuming with
// v_dot2_f32_f16 (fp32 accum). Pairing along C keeps window shifts
// dword-granular -> same proven shuffle structure. Geometry = R17's
// conflict-free one (wave-uniform row reads, 0 conflicts). Staging is
// reg-staged (global f32 -> cvt_pkrtz -> ds_write_b128), issue-early /
// write-late so the compute phase has no vmem waits.
// LDS: [2 buf][2 cpair][8 rows][264 pair-dwords] = 33792 B.
__global__ __launch_bounds__(THREADS) void cost_volume_kernel(
    const float* __restrict__ x1, const float* __restrict__ x2,
    float* __restrict__ out)
{
    __shared__ u32 smem[2 * BUFD];

    const int tid  = threadIdx.x;
    const int wave = tid >> 6;
    const int lane = tid & 63;

    const int bid = blockIdx.x;
    const bool isB = (bid >= 1536);
    int b, hout, rbase, drow;
    if (!isB) {                     // mode A: wave w -> i = w - 4 (i=-4..3)
        b     = bid & 7;
        hout  = bid >> 3;
        rbase = hout - 3;           // band[d] = x2 row rbase + d
        drow  = 7 - wave;           // row hout - i
    } else {                        // mode B: i = +4, wave = row
        const int t = bid - 1536;
        b     = t & 7;
        const int h0 = (t >> 3) << 3;
        hout  = h0 + wave;
        rbase = h0 - 4;
        drow  = wave;               // row hout - 4
    }

    // ---- staging descriptors: 1056 units/chunk, 132/wave, 3 batches ----
    // unit u -> cp=u/528, row=(u%528)/66, cu=u%66; band dwords 4cu..4cu+3
    // cover global cols 4cu-4..4cu-1 (cu in [1,64] is data, 0/65 pure halo).
    int g0, g1, g2, l0, l1, l2;
    bool wr0, wr1, wr2;
    auto mk = [&](int m, int& g, int& l, bool& wr) {
        const int q = (m << 6) + lane;
        const int u = wave * UPW + q;
        const int cp = u / 528, v = u % 528;
        const int row = v / 66, cu = v % 66;
        const int hg = rbase + row;
        wr = (q < UPW);
        const bool okl = wr & (cu >= 1) & (cu <= 64) & (hg >= 0) & (hg < HH);
        g = okl ? (((b * 64 + 2 * cp) * HH + hg) * WW + (cu << 2) - 4) : -1;
        l = cp * CPD + row * ROWD + (cu << 2);
    };
    mk(0, g0, l0, wr0);
    mk(1, g1, l1, wr1);
    mk(2, g2, l2, wr2);

    const f4 z4 = {0.f, 0.f, 0.f, 0.f};
    f4 qa0 = z4, qb0 = z4, qa1 = z4, qb1 = z4, qa2 = z4, qb2 = z4;
    auto issue_stage = [&](int n) {      // loads only (issue early)
        const int o = n * CH4;
        qa0 = (g0 >= 0) ? *(const f4*)(x2 + g0 + o)      : z4;
        qb0 = (g0 >= 0) ? *(const f4*)(x2 + g0 + o + HW) : z4;
        qa1 = (g1 >= 0) ? *(const f4*)(x2 + g1 + o)      : z4;
        qb1 = (g1 >= 0) ? *(const f4*)(x2 + g1 + o + HW) : z4;
        qa2 = (g2 >= 0) ? *(const f4*)(x2 + g2 + o)      : z4;
        qb2 = (g2 >= 0) ? *(const f4*)(x2 + g2 + o + HW) : z4;
    };
    auto write_stage = [&](int nb) {     // cvt + LDS write (late)
        u32* bp = smem + nb * BUFD;
        if (wr0) { u4 t = {pkh(qa0[0], qb0[0]), pkh(qa0[1], qb0[1]),
                           pkh(qa0[2], qb0[2]), pkh(qa0[3], qb0[3])};
                   *(u4*)(bp + l0) = t; }
        if (wr1) { u4 t = {pkh(qa1[0], qb1[0]), pkh(qa1[1], qb1[1]),
                           pkh(qa1[2], qb1[2]), pkh(qa1[3], qb1[3])};
                   *(u4*)(bp + l1) = t; }
        if (wr2) { u4 t = {pkh(qa2[0], qb2[0]), pkh(qa2[1], qb2[1]),
                           pkh(qa2[2], qb2[2]), pkh(qa2[3], qb2[3])};
                   *(u4*)(bp + l2) = t; }
    };

    // x1: register ping-pong (4 f4 per chunk, packed at consume time)
    const float* x1p = x1 + ((b * 64) * HH + hout) * WW + (lane << 2);
    f4 r0, r1, r2, r3;
    auto load_x1 = [&](int n) {
        const float* p = x1p + n * CH4;
        r0 = *(const f4*)p;
        r1 = *(const f4*)(p + HW);
        r2 = *(const f4*)(p + 2 * HW);
        r3 = *(const f4*)(p + 3 * HW);
    };

    issue_stage(0);
    load_x1(0);
    write_stage(0);
    __syncthreads();

    f4 acc0 = z4, acc1 = z4, acc2 = z4, acc3 = z4, acc4 = z4,
       acc5 = z4, acc6 = z4, acc7 = z4, acc8 = z4;

#define DJ(ACC, W, B0, B1, B2, B3)                                           \
            ACC[0] = dot2f(W[0], B0, ACC[0]);                                \
            ACC[1] = dot2f(W[1], B1, ACC[1]);                                \
            ACC[2] = dot2f(W[2], B2, ACC[2]);                                \
            ACC[3] = dot2f(W[3], B3, ACC[3]);
#define CV(BP, A0, A1, A2, A3)                                               \
        {                                                                    \
            const u4 xv0 = *(const u4*)(BP);                                 \
            const u4 xv1 = *(const u4*)((BP) + 4);                           \
            const u4 xv2 = *(const u4*)((BP) + 8);                           \
            const u4 w8v = xv0;                                              \
            const u4 w7v = __builtin_shufflevector(xv0, xv1, 1, 2, 3, 4);    \
            const u4 w6v = __builtin_shufflevector(xv0, xv1, 2, 3, 4, 5);    \
            const u4 w5v = __builtin_shufflevector(xv0, xv1, 3, 4, 5, 6);    \
            const u4 w4v = xv1;                                              \
            const u4 w3v = __builtin_shufflevector(xv1, xv2, 1, 2, 3, 4);    \
            const u4 w2v = __builtin_shufflevector(xv1, xv2, 2, 3, 4, 5);    \
            const u4 w1v = __builtin_shufflevector(xv1, xv2, 3, 4, 5, 6);    \
            const u4 w0v = xv2;                                              \
            DJ(acc0, w0v, A0, A1, A2, A3)                                    \
            DJ(acc1, w1v, A0, A1, A2, A3)                                    \
            DJ(acc2, w2v, A0, A1, A2, A3)                                    \
            DJ(acc3, w3v, A0, A1, A2, A3)                                    \
            DJ(acc4, w4v, A0, A1, A2, A3)                                    \
            DJ(acc5, w5v, A0, A1, A2, A3)                                    \
            DJ(acc6, w6v, A0, A1, A2, A3)                                    \
            DJ(acc7, w7v, A0, A1, A2, A3)                                    \
            DJ(acc8, w8v, A0, A1, A2, A3)                                    \
        }

    for (int n = 0; n < NCHUNK; ++n) {
        // pack this chunk's x1 (loads landed: previous barrier drained vmcnt)
        const u32 pa0 = pkh(r0[0], r1[0]), pa1 = pkh(r0[1], r1[1]),
                  pa2 = pkh(r0[2], r1[2]), pa3 = pkh(r0[3], r1[3]);
        const u32 pb0 = pkh(r2[0], r3[0]), pb1 = pkh(r2[1], r3[1]),
                  pb2 = pkh(r2[2], r3[2]), pb3 = pkh(r2[3], r3[3]);
        if (n + 1 < NCHUNK) { issue_stage(n + 1); load_x1(n + 1); }

        const u32* base2 = smem + (n & 1) * BUFD + drow * ROWD + (lane << 2);
        CV(base2,       pa0, pa1, pa2, pa3)   // cpair 0 (channels 4n+0,1)
        CV(base2 + CPD, pb0, pb1, pb2, pb3)   // cpair 1 (channels 4n+2,3)

        if (n + 1 < NCHUNK) write_stage((n + 1) & 1);
        __syncthreads();
    }
#undef CV
#undef DJ

    // ---- epilogue ----
    const float scale = 1.0f / 81.0f;
    const int wout = lane << 2;
    // mode A: k = (9*i + j) mod 81 = (9*wave + jj + 41) mod 81
    // mode B: i=+4 -> k = 32 + jj
#define CV_OUT(JJ)                                                           \
    {                                                                        \
        const int k = isB ? (32 + (JJ)) : (9 * wave + (JJ) + 41) % 81;       \
        float* po = out + (((long)b * 81 + k) * HH + hout) * WW + wout;      \
        *(f4*)po = acc##JJ * scale;                                          \
    }
    CV_OUT(0) CV_OUT(1) CV_OUT(2) CV_OUT(3) CV_OUT(4)
    CV_OUT(5) CV_OUT(6) CV_OUT(7) CV_OUT(8)
#undef CV_OUT
}

extern "C" void kernel_launch(void* const* d_in, const int* in_sizes, int n_in,
                              void* d_out, int out_size, void* d_ws, size_t ws_size,
                              hipStream_t stream) {
    const float* x1 = (const float*)d_in[0];
    const float* x2 = (const float*)d_in[1];
    float* out = (float*)d_out;
    // 1536 mode-A blocks (batch&7 x 192 rows, i=-4..3 per wave)
    // + 192 mode-B blocks (batch&7 x 24 row-octets, i=+4)
    dim3 grid(1536 + 192);
    dim3 block(THREADS);
    hipLaunchKernelGGL(cost_volume_kernel, grid, block, 0, stream, x1, x2, out);
}